// Round 17
// baseline (73.535 us; speedup 1.0000x reference)
//
#include <hip/hip_runtime.h>
#include <math.h>
#include <string.h>

#define HW 4096      // 64*64
#define CS 32        // channels per branch
#define NPLANES 8192 // 128 samples * 64 planes
#define PK 1024      // uint2 (8B) per plane: 1024 float4 -> 1024 uint2 = 8 KB
#define EPS 1e-5f

typedef __fp16 fp16x2 __attribute__((ext_vector_type(2)));
typedef float  vf4    __attribute__((ext_vector_type(4)));

__device__ __forceinline__ float sigmoidf_(float x) {
    return 1.0f / (1.0f + __expf(-x));
}

// pack float4 -> 2x half2 (RTZ; abs err ~0.003 @|x|<6, vs 0.104 threshold)
__device__ __forceinline__ uint2 pack4(float4 v) {
    fp16x2 a = __builtin_amdgcn_cvt_pkrtz(v.x, v.y);
    fp16x2 b = __builtin_amdgcn_cvt_pkrtz(v.z, v.w);
    uint2 r;
    memcpy(&r.x, &a, 4); memcpy(&r.y, &b, 4);
    return r;
}
__device__ __forceinline__ float4 unpack4(uint2 u) {
    fp16x2 a, b;
    memcpy(&a, &u.x, 4); memcpy(&b, &u.y, 4);
    float4 r;
    r.x = (float)a.x; r.y = (float)a.y; r.z = (float)b.x; r.w = (float)b.y;
    return r;
}
__device__ __forceinline__ float4 nt_load4(const float4* p) {
    vf4 t = __builtin_nontemporal_load((const vf4*)p);
    float4 r; r.x = t.x; r.y = t.y; r.z = t.z; r.w = t.w;
    return r;
}

// ---------------- K1: one read of x (NT when relaying); stats in fp32;
// optional fp16 packed copy of each plane into the ws relay region ----------------
__global__ __launch_bounds__(256) void pass1_kernel(
    const float* __restrict__ x, uint2* __restrict__ relay, const int use_relay,
    const float* __restrict__ gnw, const float* __restrict__ gnb,
    const float* __restrict__ sw,  const float* __restrict__ sb,
    float* __restrict__ sums0, float* __restrict__ mu1,
    float* __restrict__ rs1,   float* __restrict__ sumxs) {
    const int P = blockIdx.x;
    const int n = P >> 6, cc = P & 63;
    const int tid = threadIdx.x;
    const float4* xp = (const float4*)(x + (size_t)P * HW);
    uint2* pp = relay + (size_t)P * PK;   // 8 KB packed per plane
    __shared__ float ls[4];
    __shared__ float bc[2];

    if (cc < CS) {
        float s = 0.f;
#pragma unroll
        for (int k = 0; k < 4; ++k) {
            float4 v = use_relay ? nt_load4(xp + tid + k * 256)
                                 : xp[tid + k * 256];
            if (use_relay) pp[tid + k * 256] = pack4(v);  // L3-resident relay
            s += v.x + v.y + v.z + v.w;
        }
        for (int off = 32; off > 0; off >>= 1) s += __shfl_down(s, off, 64);
        const int wave = tid >> 6, lane = tid & 63;
        if (lane == 0) ls[wave] = s;
        __syncthreads();
        if (tid == 0) sums0[n * CS + cc] = ls[0] + ls[1] + ls[2] + ls[3];
    } else {
        const int c = cc - CS;
        float4 v[4];
        float s = 0.f, s2 = 0.f;
#pragma unroll
        for (int k = 0; k < 4; ++k) {
            v[k] = use_relay ? nt_load4(xp + tid + k * 256)
                             : xp[tid + k * 256];
            if (use_relay) pp[tid + k * 256] = pack4(v[k]);
            s  += v[k].x + v[k].y + v[k].z + v[k].w;
            s2 += v[k].x * v[k].x + v[k].y * v[k].y
                + v[k].z * v[k].z + v[k].w * v[k].w;
        }
        for (int off = 32; off > 0; off >>= 1) {
            s  += __shfl_down(s, off, 64);
            s2 += __shfl_down(s2, off, 64);
        }
        __shared__ float ls2[4];
        const int wave = tid >> 6, lane = tid & 63;
        if (lane == 0) { ls[wave] = s; ls2[wave] = s2; }
        __syncthreads();
        if (tid == 0) {
            float st  = ls[0] + ls[1] + ls[2] + ls[3];
            float s2t = ls2[0] + ls2[1] + ls2[2] + ls2[3];
            float mu  = st * (1.0f / HW);
            float var = s2t * (1.0f / HW) - mu * mu;
            float rs  = rsqrtf(var + EPS);
            mu1[n * CS + c] = mu;
            rs1[n * CS + c] = rs;
            bc[0] = mu; bc[1] = rs;
        }
        __syncthreads();
        const float mu = bc[0], rs = bc[1];
        const float a  = gnw[c] * rs;
        const float b0 = gnb[c] - mu * a;
        const float sbv = sb[c];
        const float4* wp = (const float4*)(sw + (size_t)c * HW);
        float sx = 0.f;
#pragma unroll
        for (int k = 0; k < 4; ++k) {
            float4 w = wp[tid + k * 256];
            sx += v[k].x * sigmoidf_(w.x * (v[k].x * a + b0) + sbv);
            sx += v[k].y * sigmoidf_(w.y * (v[k].y * a + b0) + sbv);
            sx += v[k].z * sigmoidf_(w.z * (v[k].z * a + b0) + sbv);
            sx += v[k].w * sigmoidf_(w.w * (v[k].w * a + b0) + sbv);
        }
        for (int off = 32; off > 0; off >>= 1) sx += __shfl_down(sx, off, 64);
        __syncthreads();   // ls reuse
        if (lane == 0) ls[wave] = sx;
        __syncthreads();
        if (tid == 0) sumxs[n * CS + c] = ls[0] + ls[1] + ls[2] + ls[3];
    }
}

// ---------------- K2: fused gates + output; x from the ws relay (L3-hot)
// or re-read from x (fallback) ----------------
__global__ __launch_bounds__(256) void out_kernel(
    const float* __restrict__ x, float* __restrict__ out,
    const uint2* __restrict__ relay, const int use_relay,
    const float* __restrict__ sums0,
    const float* __restrict__ mu1, const float* __restrict__ rs1,
    const float* __restrict__ sumxs,
    const float* __restrict__ cw,  const float* __restrict__ cb,
    const float* __restrict__ gnw, const float* __restrict__ gnb,
    const float* __restrict__ sw,  const float* __restrict__ sb,
    const float* __restrict__ fc1w, const float* __restrict__ fc1b,
    const float* __restrict__ lnw, const float* __restrict__ lnb,
    const float* __restrict__ fc2w, const float* __restrict__ fc2b) {
    const int P = blockIdx.x;
    const int n = P >> 6, cc = P & 63;
    const int tid = threadIdx.x;
    const int branch = (cc >= CS);
    const int c0 = cc & 31;

    // ---- issue relay reads EARLY (latency hides under the gate MLP) ----
    const uint2* pp = relay + (size_t)P * PK;
    uint2 pu[4];
    if (use_relay) {
#pragma unroll
        for (int k = 0; k < 4; ++k) pu[k] = pp[tid + k * 256];
    }

    __shared__ float pS[CS], qS[CS], rS[CS], g0S[CS];
    __shared__ float scaleS;

    // ---- redundant per-block gate MLP (threads of wave 0) ----
    if (tid < CS) {
        float pv;
        if (!branch) {
            float mean = sums0[n * CS + tid] * (1.0f / HW);
            float g0 = sigmoidf_(cw[tid] * mean + cb[tid]);
            g0S[tid] = g0;
            pv = mean * (1.0f - g0);          // mean of x_reid_0
        } else {
            pv = mu1[n * CS + tid] - sumxs[n * CS + tid] * (1.0f / HW);
        }
        pS[tid] = pv;
    }
    __syncthreads();
    if (tid < CS) {
        float qv = fc1b[tid];
        for (int j = 0; j < CS; ++j) qv += fc1w[tid * CS + j] * pS[j];
        qS[tid] = qv;
    }
    __syncthreads();
    if (tid < CS) {
        float mu = 0.f;
        for (int j = 0; j < CS; ++j) mu += qS[j];
        mu *= (1.0f / CS);
        float var = 0.f;
        for (int j = 0; j < CS; ++j) { float d = qS[j] - mu; var += d * d; }
        var *= (1.0f / CS);
        float qn = (qS[tid] - mu) * rsqrtf(var + EPS) * lnw[tid] + lnb[tid];
        rS[tid] = fmaxf(qn, 0.f);
    }
    __syncthreads();
    if (tid < 64) {   // whole wave 0 active -> well-defined shuffles
        float t = (tid < CS) ? fc2w[c0 * CS + tid] * rS[tid] : 0.f;
        for (int off = 32; off > 0; off >>= 1) t += __shfl_down(t, off, 64);
        if (tid == 0) {
            float gd = sigmoidf_(t + fc2b[c0]);
            scaleS = branch ? gd : (g0S[c0] + (1.0f - g0S[c0]) * gd);
        }
    }
    __syncthreads();

    const float4* xp = (const float4*)(x + (size_t)P * HW);
    float4* op = (float4*)(out + (size_t)P * HW);

    if (!branch) {
        const float scale = scaleS;
#pragma unroll
        for (int k = 0; k < 4; ++k) {
            float4 v = use_relay ? unpack4(pu[k]) : xp[tid + k * 256];
            v.x *= scale; v.y *= scale; v.z *= scale; v.w *= scale;
            op[tid + k * 256] = v;
        }
    } else {
        const float g  = scaleS;
        const float mu = mu1[n * CS + c0], rs = rs1[n * CS + c0];
        const float a  = gnw[c0] * rs;
        const float b0 = gnb[c0] - mu * a;
        const float sbv = sb[c0];
        const float4* wp = (const float4*)(sw + (size_t)c0 * HW);
#pragma unroll
        for (int k = 0; k < 4; ++k) {
            float4 v = use_relay ? unpack4(pu[k]) : xp[tid + k * 256];
            float4 w = wp[tid + k * 256];
            float4 o; float sg;
            sg = sigmoidf_(w.x * (v.x * a + b0) + sbv); o.x = v.x * (sg + (1.f - sg) * g);
            sg = sigmoidf_(w.y * (v.y * a + b0) + sbv); o.y = v.y * (sg + (1.f - sg) * g);
            sg = sigmoidf_(w.z * (v.z * a + b0) + sbv); o.z = v.z * (sg + (1.f - sg) * g);
            sg = sigmoidf_(w.w * (v.w * a + b0) + sbv); o.w = v.w * (sg + (1.f - sg) * g);
            op[tid + k * 256] = o;
        }
    }
}

extern "C" void kernel_launch(void* const* d_in, const int* in_sizes, int n_in,
                              void* d_out, int out_size, void* d_ws, size_t ws_size,
                              hipStream_t stream) {
    const float* x    = (const float*)d_in[0];
    const float* cw   = (const float*)d_in[1];
    const float* cb   = (const float*)d_in[2];
    const float* sw   = (const float*)d_in[3];
    const float* sb   = (const float*)d_in[4];
    const float* gnw  = (const float*)d_in[5];
    const float* gnb  = (const float*)d_in[6];
    const float* fc1w = (const float*)d_in[7];
    const float* fc1b = (const float*)d_in[8];
    const float* lnw  = (const float*)d_in[9];
    const float* lnb  = (const float*)d_in[10];
    const float* fc2w = (const float*)d_in[11];
    const float* fc2b = (const float*)d_in[12];
    float* out = (float*)d_out;
    float* ws  = (float*)d_ws;

    float* sums0 = ws;             // 4096
    float* mu1   = ws + 4096;      // 4096
    float* rs1   = ws + 8192;      // 4096
    float* sumxs = ws + 12288;     // 4096
    uint2* relay = (uint2*)(ws + 16384);           // 64 MiB packed relay
    const size_t need = (size_t)16384 * 4 + (size_t)NPLANES * PK * 8;
    const int use_relay = (ws_size >= need) ? 1 : 0;

    pass1_kernel<<<NPLANES, 256, 0, stream>>>(x, relay, use_relay,
                                              gnw, gnb, sw, sb,
                                              sums0, mu1, rs1, sumxs);
    out_kernel<<<NPLANES, 256, 0, stream>>>(x, out, relay, use_relay,
                                            sums0, mu1, rs1, sumxs,
                                            cw, cb, gnw, gnb, sw, sb,
                                            fc1w, fc1b, lnw, lnb, fc2w, fc2b);
}